// Round 2
// baseline (438.120 us; speedup 1.0000x reference)
//
#include <hip/hip_runtime.h>

// Embedding: out[t, e] = W[e, x[t]] + b[e]
//   x: [32*2048] int32 token ids in [0, 100000)
//   W: [256, 100000] f32 row-major  (so a token's embedding is a COLUMN, stride 100000)
//   b: [256] f32
//   out: [65536, 256] f32
//
// Layout: 64 lanes per token, 4 consecutive e per lane (float4).
//  - stores: out[t*256 + lane*4 ..+3] -> contiguous 1 KiB per token per wave, fully coalesced
//  - gather reads: W[(e)*V + v] stride-V scalar loads, inherently uncoalesced; W (102 MB)
//    fits in the 256 MiB L3 so repeats are absorbed there.

#define VOCAB 100000
#define EMBED 256
#define NTOK  (32 * 2048)

__global__ __launch_bounds__(256) void embed_gather(
    const int* __restrict__ x,
    const float* __restrict__ W,
    const float* __restrict__ bias,
    float* __restrict__ out)
{
    const int tid   = blockIdx.x * blockDim.x + threadIdx.x;
    const int token = tid >> 6;          // 64 threads per token
    const int e     = (tid & 63) << 2;   // this lane covers e .. e+3
    if (token >= NTOK) return;

    const int v = x[token];              // wave-uniform broadcast load

    const float4 bv = *reinterpret_cast<const float4*>(bias + e);

    float4 r;
    r.x = W[(size_t)(e + 0) * VOCAB + v] + bv.x;
    r.y = W[(size_t)(e + 1) * VOCAB + v] + bv.y;
    r.z = W[(size_t)(e + 2) * VOCAB + v] + bv.z;
    r.w = W[(size_t)(e + 3) * VOCAB + v] + bv.w;

    *reinterpret_cast<float4*>(out + (size_t)token * EMBED + e) = r;
}

extern "C" void kernel_launch(void* const* d_in, const int* in_sizes, int n_in,
                              void* d_out, int out_size, void* d_ws, size_t ws_size,
                              hipStream_t stream)
{
    const int*   x = (const int*)d_in[0];
    const float* W = (const float*)d_in[1];
    const float* b = (const float*)d_in[2];
    float*     out = (float*)d_out;

    const int total_threads = NTOK * 64;     // 64 lanes per token
    const int block = 256;
    const int grid  = total_threads / block; // 16384 blocks

    embed_gather<<<grid, block, 0, stream>>>(x, W, b, out);
}

// Round 3
// 207.575 us; speedup vs baseline: 2.1107x; 2.1107x over previous
//
#include <hip/hip_runtime.h>

// Embedding: out[t, :] = W[:, x[t]] + b
// Two-phase: (1) WT[v][e] = W[e][v] + b[e]  (LDS-tiled transpose, bias fused)
//            (2) out[t][:] = WT[x[t]][:]     (coalesced row copy, 1 wave/token)
//
// Why: the direct column-gather pulls a 64B line per element (16x over-fetch,
// measured FETCH_SIZE 1.03 GB, round 2). Transposing costs 2x102 MB coalesced
// and turns the gather into contiguous 1 KB row reads.

#define VOCAB 100000
#define EMBED 256
#define NTOK  (32 * 2048)
#define WT_BYTES ((size_t)VOCAB * EMBED * 4)

// ---- Phase 1: transpose + bias. W [256,100000] -> WT [100000,256] ----
// grid (3125, 8), block (32, 8). 32x32 tiles; V%32==0, E%32==0: no bounds checks.
__global__ __launch_bounds__(256) void transpose_bias(
    const float* __restrict__ W,
    const float* __restrict__ bias,
    float* __restrict__ WT)
{
    __shared__ float tile[32][33];   // +1 pad: conflict-free transpose

    const int v0 = blockIdx.x * 32;  // vocab tile origin
    const int e0 = blockIdx.y * 32;  // embed tile origin
    const int tx = threadIdx.x;      // 0..31
    const int ty = threadIdx.y;      // 0..7

    // load 32x32 tile of W: rows e0+ty+j, cols v0+tx  (coalesced over tx)
    #pragma unroll
    for (int j = 0; j < 32; j += 8) {
        tile[ty + j][tx] = W[(size_t)(e0 + ty + j) * VOCAB + (v0 + tx)];
    }
    __syncthreads();

    // store transposed: rows v0+ty+j, cols e0+tx  (coalesced over tx), + bias[e]
    const float be = bias[e0 + tx];
    #pragma unroll
    for (int j = 0; j < 32; j += 8) {
        WT[(size_t)(v0 + ty + j) * EMBED + (e0 + tx)] = tile[tx][ty + j] + be;
    }
}

// ---- Phase 2: row gather. out[t][:] = WT[x[t]][:] ----
// 64 lanes per token, float4 per lane -> 1 KB contiguous read + write per wave.
__global__ __launch_bounds__(256) void embed_copy(
    const int* __restrict__ x,
    const float* __restrict__ WT,
    float* __restrict__ out)
{
    const int tid   = blockIdx.x * blockDim.x + threadIdx.x;
    const int token = tid >> 6;
    const int e     = (tid & 63) << 2;
    if (token >= NTOK) return;

    const int v = x[token];   // wave-uniform

    const float4 r = *reinterpret_cast<const float4*>(WT + (size_t)v * EMBED + e);
    __builtin_nontemporal_store(r.x, out + (size_t)token * EMBED + e + 0);
    __builtin_nontemporal_store(r.y, out + (size_t)token * EMBED + e + 1);
    __builtin_nontemporal_store(r.z, out + (size_t)token * EMBED + e + 2);
    __builtin_nontemporal_store(r.w, out + (size_t)token * EMBED + e + 3);
}

// ---- Fallback (ws too small): round-2 direct column gather ----
__global__ __launch_bounds__(256) void embed_gather_direct(
    const int* __restrict__ x,
    const float* __restrict__ W,
    const float* __restrict__ bias,
    float* __restrict__ out)
{
    const int tid   = blockIdx.x * blockDim.x + threadIdx.x;
    const int token = tid >> 6;
    const int e     = (tid & 63) << 2;
    if (token >= NTOK) return;

    const int v = x[token];
    const float4 bv = *reinterpret_cast<const float4*>(bias + e);
    float4 r;
    r.x = W[(size_t)(e + 0) * VOCAB + v] + bv.x;
    r.y = W[(size_t)(e + 1) * VOCAB + v] + bv.y;
    r.z = W[(size_t)(e + 2) * VOCAB + v] + bv.z;
    r.w = W[(size_t)(e + 3) * VOCAB + v] + bv.w;
    *reinterpret_cast<float4*>(out + (size_t)token * EMBED + e) = r;
}

extern "C" void kernel_launch(void* const* d_in, const int* in_sizes, int n_in,
                              void* d_out, int out_size, void* d_ws, size_t ws_size,
                              hipStream_t stream)
{
    const int*   x = (const int*)d_in[0];
    const float* W = (const float*)d_in[1];
    const float* b = (const float*)d_in[2];
    float*     out = (float*)d_out;

    if (ws_size >= WT_BYTES) {
        float* WT = (float*)d_ws;

        dim3 tgrid(VOCAB / 32, EMBED / 32);   // (3125, 8)
        dim3 tblock(32, 8);
        transpose_bias<<<tgrid, tblock, 0, stream>>>(W, b, WT);

        const int total_threads = NTOK * 64;
        embed_copy<<<total_threads / 256, 256, 0, stream>>>(x, WT, out);
    } else {
        const int total_threads = NTOK * 64;
        embed_gather_direct<<<total_threads / 256, 256, 0, stream>>>(x, W, b, out);
    }
}

// Round 4
// 190.079 us; speedup vs baseline: 2.3049x; 1.0920x over previous
//
#include <hip/hip_runtime.h>

// Embedding: out[t, :] = W[:, x[t]] + b   (W [256,100000] row-major f32)
//
// Scatter formulation (structural optimum ~167 MB total HBM traffic):
//   k0: zero bin counters (6250 ints)
//   k1: bucket tokens by vocab tile bin = x[t]>>4 (atomicAdd, packed entry t|(i<<16))
//   k2: one block per 16-wide W tile: stage 16x256 tile to LDS (every 64B line of W
//       read exactly once, line-aligned since row stride 400000B % 64 == 0),
//       then per token in bin write out[t][0:256] coalesced (+bias), nontemporal.
//   k3: cleanup for overflowed bins (CAP=256 vs Poisson mean 10.5 -> never taken;
//       correctness net only).
//
// Round-3 lesson: materializing WT costs 102MB write + ~60MB re-read of pure
// overhead; scatter removes it.

#define VOCAB 100000
#define EMBED 256
#define NTOK  (32 * 2048)
#define NTILE (VOCAB / 16)        // 6250 vocab tiles of 16 columns
#define CAP   256                 // slots per bin (avg occupancy 10.5)

// workspace layout (ints): [0,8192) cnt (6250 used) | [8192, 8192+NTILE*CAP) list | flags [NTOK)
#define WS_CNT_OFF   0
#define WS_LIST_OFF  8192
#define WS_FLAG_OFF  (8192 + NTILE * CAP)
#define WS_INTS      (WS_FLAG_OFF + NTOK)

__global__ __launch_bounds__(256) void k0_zero(int* __restrict__ cnt)
{
    int i = blockIdx.x * 256 + threadIdx.x;
    if (i < NTILE) cnt[i] = 0;
}

__global__ __launch_bounds__(256) void k1_bucket(
    const int* __restrict__ x,
    int* __restrict__ cnt,
    int* __restrict__ list,
    int* __restrict__ flags)
{
    int t = blockIdx.x * 256 + threadIdx.x;
    if (t >= NTOK) return;
    int v   = x[t];
    int bin = v >> 4;
    int i   = v & 15;
    int pos = atomicAdd(&cnt[bin], 1);
    int ovf = (pos >= CAP);
    if (!ovf) list[bin * CAP + pos] = t | (i << 16);
    flags[t] = ovf;                     // written for ALL t (ws is poisoned)
}

__global__ __launch_bounds__(256) void k2_scatter(
    const float* __restrict__ W,
    const float* __restrict__ bias,
    const int* __restrict__ cnt,
    const int* __restrict__ list,
    float* __restrict__ out)
{
    __shared__ float tileT[16 * 260];   // [i][e], stride 260 (16B-aligned rows, pad)

    const int bin = blockIdx.x;
    const int v0  = bin << 4;
    const int t   = threadIdx.x;

    // stage: 4 iters x 256 threads x float4 = 16*256 floats.
    // lane group of 4 covers one 64B line; every W line touched exactly once.
    #pragma unroll
    for (int j = 0; j < 4; ++j) {
        const int e  = j * 64 + (t >> 2);
        const int i4 = (t & 3) << 2;
        const float4 w = *reinterpret_cast<const float4*>(
            W + (size_t)e * VOCAB + v0 + i4);
        tileT[(i4 + 0) * 260 + e] = w.x;
        tileT[(i4 + 1) * 260 + e] = w.y;
        tileT[(i4 + 2) * 260 + e] = w.z;
        tileT[(i4 + 3) * 260 + e] = w.w;
    }
    __syncthreads();

    int n = cnt[bin];
    if (n > CAP) n = CAP;

    const int wave = t >> 6;
    const int lane = t & 63;
    const float4 bv = *reinterpret_cast<const float4*>(bias + lane * 4);

    for (int k = wave; k < n; k += 4) {
        const int packed = list[bin * CAP + k];
        const int tok = packed & 0xFFFF;
        const int i   = packed >> 16;
        const float* src = &tileT[i * 260 + lane * 4];
        float* dst = out + (size_t)tok * EMBED + lane * 4;
        __builtin_nontemporal_store(src[0] + bv.x, dst + 0);
        __builtin_nontemporal_store(src[1] + bv.y, dst + 1);
        __builtin_nontemporal_store(src[2] + bv.z, dst + 2);
        __builtin_nontemporal_store(src[3] + bv.w, dst + 3);
    }
}

__global__ __launch_bounds__(256) void k3_cleanup(
    const int* __restrict__ x,
    const float* __restrict__ W,
    const float* __restrict__ bias,
    const int* __restrict__ flags,
    float* __restrict__ out)
{
    int t = blockIdx.x * 256 + threadIdx.x;
    if (t >= NTOK) return;
    if (!flags[t]) return;              // never taken for this input
    int v = x[t];
    for (int e = 0; e < EMBED; ++e)
        out[(size_t)t * EMBED + e] = W[(size_t)e * VOCAB + v] + bias[e];
}

// fallback: direct column gather (round-2 kernel), if ws too small
__global__ __launch_bounds__(256) void embed_gather_direct(
    const int* __restrict__ x,
    const float* __restrict__ W,
    const float* __restrict__ bias,
    float* __restrict__ out)
{
    const int tid   = blockIdx.x * blockDim.x + threadIdx.x;
    const int token = tid >> 6;
    const int e     = (tid & 63) << 2;
    if (token >= NTOK) return;
    const int v = x[token];
    const float4 bv = *reinterpret_cast<const float4*>(bias + e);
    float4 r;
    r.x = W[(size_t)(e + 0) * VOCAB + v] + bv.x;
    r.y = W[(size_t)(e + 1) * VOCAB + v] + bv.y;
    r.z = W[(size_t)(e + 2) * VOCAB + v] + bv.z;
    r.w = W[(size_t)(e + 3) * VOCAB + v] + bv.w;
    *reinterpret_cast<float4*>(out + (size_t)token * EMBED + e) = r;
}

extern "C" void kernel_launch(void* const* d_in, const int* in_sizes, int n_in,
                              void* d_out, int out_size, void* d_ws, size_t ws_size,
                              hipStream_t stream)
{
    const int*   x = (const int*)d_in[0];
    const float* W = (const float*)d_in[1];
    const float* b = (const float*)d_in[2];
    float*     out = (float*)d_out;

    if (ws_size >= (size_t)WS_INTS * sizeof(int)) {
        int* ws    = (int*)d_ws;
        int* cnt   = ws + WS_CNT_OFF;
        int* list  = ws + WS_LIST_OFF;
        int* flags = ws + WS_FLAG_OFF;

        k0_zero   <<<(NTILE + 255) / 256, 256, 0, stream>>>(cnt);
        k1_bucket <<<NTOK / 256,          256, 0, stream>>>(x, cnt, list, flags);
        k2_scatter<<<NTILE,               256, 0, stream>>>(W, b, cnt, list, out);
        k3_cleanup<<<NTOK / 256,          256, 0, stream>>>(x, W, b, flags, out);
    } else {
        embed_gather_direct<<<NTOK * 64 / 256, 256, 0, stream>>>(x, W, b, out);
    }
}